// Round 16
// baseline (230.161 us; speedup 1.0000x reference)
//
#include <hip/hip_runtime.h>
#include <hip/hip_bf16.h>

// AttnBlock: B=8, C=512, N=2048, G=32.
// All GEMMs NT: Out[m][n] = sum_k A[m][k] * Bt[n][k].
// R16 = R15 with the GEMM core moved to v_mfma_f32_32x32x16_bf16 (gemm14):
//   measured 2382 TF vs 2075 for 16x16x32 (+15% pipe rate), and 2x FLOP per
//   fragment-pair -> 25% fewer LDS reads at a 128x64 wave tile.
//   256x128 tile, 256 thr, 4 waves (2x2 of 128x64), single-buffered 48KB LDS
//   (3 blocks/CU), m97 2-barrier loop, T2 swizzle (conflict-free for 32-lane rows).
//   A/B frag: lane l -> row l&31, k = (l>>5)*8+j. C/D (m74/m101-verified):
//   n = lane&31, m = (r&3) + 8*(r>>2) + 4*(lane>>5), r in [0,16).
// Fusions kept: S epilogue = exp(s*scale) + LDS rowsum reduce -> 1 atomic/row;
// PV epilogue * rinv[row]; proj epilogue + bias + residual. XCD pinning kept.

typedef __attribute__((ext_vector_type(8))) short short8;
typedef __attribute__((ext_vector_type(16))) float f32x16;
typedef unsigned short u16;

#define BK 64

__device__ __forceinline__ u16 f2bf(float f) {
  __hip_bfloat16 h = __float2bfloat16(f);
  return __builtin_bit_cast(u16, h);
}
__device__ __forceinline__ float bf2f(u16 u) {
  return __uint_as_float(((unsigned)u) << 16);
}

__device__ __forceinline__ void gload_lds16(const void* g, void* l) {
  __builtin_amdgcn_global_load_lds((const __attribute__((address_space(1))) void*)g,
                                   (__attribute__((address_space(3))) void*)l, 16, 0, 0);
}

// MODE 0: bf16 out = acc + bias[col]     MODE 1: bf16 out = acc + bias[row]
// MODE 2: bf16 out = exp(acc*scale); LDS rowsum reduce -> 1 atomicAdd/row
// MODE 4: f32  out = acc + bias[row] + aux[b*sRes + row*ldo + col]  (residual)
// MODE 5: bf16 out = acc * aux[b*sRes + row]                        (rinv)
// Grid: 1-D, gid = t*8 + b;  t = by*GX + bx;  m0 = by*256 + b*mOffB; n0 = bx*128.
template <int MODE>
__global__ __launch_bounds__(256) void gemm14(
    const u16* __restrict__ A, const u16* __restrict__ Bt, void* __restrict__ OutV,
    const float* __restrict__ bias, float* __restrict__ aux,
    int K, int lda, int ldb, int ldo, int GX, int mOffB,
    long sA, long sBt, long sOut, long sRes, float scale) {
  __shared__ __align__(16) u16 lds_all[(256 + 128) * BK];  // 48 KB: As(32K) | Bs(16K)
  u16* As = lds_all;
  u16* Bs = lds_all + 256 * BK;

  const int gid = blockIdx.x;
  const int b = gid & 7;  // batch == XCD (round-robin dispatch)
  const int t0 = gid >> 3;
  const int bx = t0 % GX;
  const int by = t0 / GX;
  const u16* Ab = A + (long)b * sA;
  const u16* Bb = Bt + (long)b * sBt;
  const int tid = threadIdx.x;
  const int lane = tid & 63;
  const int wid = tid >> 6;
  const int wmL = (wid >> 1) * 128;  // wave m base (0 or 128)
  const int wnL = (wid & 1) * 64;    // wave n base (0 or 64)
  const int m0 = by * 256 + b * mOffB;
  const int n0 = bx * 128;
  const int l31 = lane & 31;
  const int hi5 = lane >> 5;
  const int sw = l31 & 7;  // swizzle term: 16B-slot ^= (row&7), row ≡ l31 (mod 32)

  f32x16 acc[4][2];
#pragma unroll
  for (int i = 0; i < 4; ++i)
#pragma unroll
    for (int j = 0; j < 2; ++j) acc[i][j] = (f32x16)(0.f);

  for (int ks = 0; ks < K; ks += BK) {
    // stage A (256x64 = 2048 chunks, 8/thr) and B (128x64 = 1024 chunks, 4/thr)
#pragma unroll
    for (int i = 0; i < 8; ++i) {
      const int c = tid + i * 256;
      const int row = c >> 3;
      const int gslot = (c & 7) ^ (row & 7);
      gload_lds16(Ab + (long)(m0 + row) * lda + ks + gslot * 8, (void*)(As + c * 8));
    }
#pragma unroll
    for (int i = 0; i < 4; ++i) {
      const int c = tid + i * 256;
      const int row = c >> 3;
      const int gslot = (c & 7) ^ (row & 7);
      gload_lds16(Bb + (long)(n0 + row) * ldb + ks + gslot * 8, (void*)(Bs + c * 8));
    }
    __syncthreads();

#pragma unroll
    for (int kst = 0; kst < 4; ++kst) {  // four K=16 substeps
      short8 af[4], bf[2];
#pragma unroll
      for (int mb = 0; mb < 4; ++mb)
        af[mb] = *(const short8*)(As + (wmL + mb * 32 + l31) * BK +
                                  ((kst * 2 + hi5) ^ sw) * 8);
#pragma unroll
      for (int nb = 0; nb < 2; ++nb)
        bf[nb] = *(const short8*)(Bs + (wnL + nb * 32 + l31) * BK +
                                  ((kst * 2 + hi5) ^ sw) * 8);
#pragma unroll
      for (int mb = 0; mb < 4; ++mb)
#pragma unroll
        for (int nb = 0; nb < 2; ++nb)
          acc[mb][nb] = __builtin_amdgcn_mfma_f32_32x32x16_bf16(af[mb], bf[nb],
                                                               acc[mb][nb], 0, 0, 0);
    }
    __syncthreads();
  }

  // epilogue: D n = lane&31, m = (r&3) + 8*(r>>2) + 4*hi5  (r in [0,16))
  if constexpr (MODE == 2) {
    float* rs = (float*)lds_all;  // [256][33] floats = 33.8 KB (dead GEMM LDS)
#pragma unroll
    for (int mb = 0; mb < 4; ++mb) {
#pragma unroll
      for (int r = 0; r < 16; ++r) {
        const int mL = wmL + mb * 32 + (r & 3) + 8 * (r >> 2) + 4 * hi5;
        const int row = m0 + mL;
        float part = 0.f;
#pragma unroll
        for (int nb = 0; nb < 2; ++nb) {
          const int col = n0 + wnL + nb * 32 + l31;
          const long oidx = (long)b * sOut + (long)row * ldo + col;
          const u16 pe = f2bf(__expf(acc[mb][nb][r] * scale));
          ((u16*)OutV)[oidx] = pe;
          part += bf2f(pe);  // sum what PV will actually read
        }
        rs[mL * 33 + (wnL >> 1) + l31] = part;  // wnL/2 = 0 or 32... (wnL>>1)=0/32
      }
    }
    __syncthreads();
    if (tid < 256) {
      float s = 0.f;
#pragma unroll
      for (int j = 0; j < 32; ++j) s += rs[tid * 33 + ((wnL >> 1) ? 0 : 0) + j];
      // partials live at cols 0..31 (wave n-half 0) and 32... but (wnL>>1) is 0 or 32:
      // cols 0..63 total; sum both halves:
#pragma unroll
      for (int j = 32; j < 33; ++j) (void)j;
      atomicAdd(&aux[(long)b * sRes + m0 + tid], s);
    }
  } else {
#pragma unroll
    for (int mb = 0; mb < 4; ++mb) {
#pragma unroll
      for (int nb = 0; nb < 2; ++nb) {
#pragma unroll
        for (int r = 0; r < 16; ++r) {
          const int row = m0 + wmL + mb * 32 + (r & 3) + 8 * (r >> 2) + 4 * hi5;
          const int col = n0 + wnL + nb * 32 + l31;
          const long oidx = (long)b * sOut + (long)row * ldo + col;
          const float v = acc[mb][nb][r];
          if (MODE == 0) {
            ((u16*)OutV)[oidx] = f2bf(v + bias[col]);
          } else if (MODE == 1) {
            ((u16*)OutV)[oidx] = f2bf(v + bias[row]);
          } else if (MODE == 5) {
            ((u16*)OutV)[oidx] = f2bf(v * aux[(long)b * sRes + row]);
          } else {
            const float r2 = aux[(long)b * sRes + (long)row * ldo + col];
            ((float*)OutV)[oidx] = v + bias[row] + r2;
          }
        }
      }
    }
  }
}

// MODE 2 rowsum fix: partials at rs[mL][ (wnL>>1) + l31 ] give cols 0..31 (wave-n 0)
// and 32..63 (wave-n 1). The reducer above must sum 64 cols. Specialization below.
template <>
__global__ __launch_bounds__(256) void gemm14<2>(
    const u16* __restrict__ A, const u16* __restrict__ Bt, void* __restrict__ OutV,
    const float* __restrict__ bias, float* __restrict__ aux,
    int K, int lda, int ldb, int ldo, int GX, int mOffB,
    long sA, long sBt, long sOut, long sRes, float scale) {
  __shared__ __align__(16) u16 lds_all[(256 + 128) * BK];  // 48 KB
  u16* As = lds_all;
  u16* Bs = lds_all + 256 * BK;

  const int gid = blockIdx.x;
  const int b = gid & 7;
  const int t0 = gid >> 3;
  const int bx = t0 % GX;
  const int by = t0 / GX;
  const u16* Ab = A + (long)b * sA;
  const u16* Bb = Bt + (long)b * sBt;
  const int tid = threadIdx.x;
  const int lane = tid & 63;
  const int wid = tid >> 6;
  const int wmL = (wid >> 1) * 128;
  const int wnL = (wid & 1) * 64;
  const int m0 = by * 256 + b * mOffB;
  const int n0 = bx * 128;
  const int l31 = lane & 31;
  const int hi5 = lane >> 5;
  const int sw = l31 & 7;

  f32x16 acc[4][2];
#pragma unroll
  for (int i = 0; i < 4; ++i)
#pragma unroll
    for (int j = 0; j < 2; ++j) acc[i][j] = (f32x16)(0.f);

  for (int ks = 0; ks < K; ks += BK) {
#pragma unroll
    for (int i = 0; i < 8; ++i) {
      const int c = tid + i * 256;
      const int row = c >> 3;
      const int gslot = (c & 7) ^ (row & 7);
      gload_lds16(Ab + (long)(m0 + row) * lda + ks + gslot * 8, (void*)(As + c * 8));
    }
#pragma unroll
    for (int i = 0; i < 4; ++i) {
      const int c = tid + i * 256;
      const int row = c >> 3;
      const int gslot = (c & 7) ^ (row & 7);
      gload_lds16(Bb + (long)(n0 + row) * ldb + ks + gslot * 8, (void*)(Bs + c * 8));
    }
    __syncthreads();
#pragma unroll
    for (int kst = 0; kst < 4; ++kst) {
      short8 af[4], bf[2];
#pragma unroll
      for (int mb = 0; mb < 4; ++mb)
        af[mb] = *(const short8*)(As + (wmL + mb * 32 + l31) * BK +
                                  ((kst * 2 + hi5) ^ sw) * 8);
#pragma unroll
      for (int nb = 0; nb < 2; ++nb)
        bf[nb] = *(const short8*)(Bs + (wnL + nb * 32 + l31) * BK +
                                  ((kst * 2 + hi5) ^ sw) * 8);
#pragma unroll
      for (int mb = 0; mb < 4; ++mb)
#pragma unroll
        for (int nb = 0; nb < 2; ++nb)
          acc[mb][nb] = __builtin_amdgcn_mfma_f32_32x32x16_bf16(af[mb], bf[nb],
                                                               acc[mb][nb], 0, 0, 0);
    }
    __syncthreads();
  }

  // epilogue: exp store + rowsum. partial col slot = (wid&1)*32 + l31 in [0,64)
  float* rs = (float*)lds_all;  // [256][65] floats = 66.5KB? NO -> use [256][33] x2 waves summed:
  // store summed-over-nb partial at [mL][(wid&1)*32 + l31] requires 64 cols.
  // 256*65*4 = 66KB > 48KB. Instead: sum nb pairs AND fold the two n-waves via
  // two sequential stores with += after a barrier ordering trick is racy; so use
  // [256][33] and have n-wave 1 add into n-wave 0's slots with atomic-free split:
  // slot = l31, two waves write different halves? They'd collide. Resolution:
  // rs[256][33]: n-wave 0 writes, barrier, n-wave 1 adds, barrier, reduce 32.
#pragma unroll
  for (int mb = 0; mb < 4; ++mb) {
#pragma unroll
    for (int r = 0; r < 16; ++r) {
      const int mL = wmL + mb * 32 + (r & 3) + 8 * (r >> 2) + 4 * hi5;
      const int row = m0 + mL;
      float part = 0.f;
#pragma unroll
      for (int nb = 0; nb < 2; ++nb) {
        const int col = n0 + wnL + nb * 32 + l31;
        const long oidx = (long)b * sOut + (long)row * ldo + col;
        const u16 pe = f2bf(__expf(acc[mb][nb][r] * scale));
        ((u16*)OutV)[oidx] = pe;
        part += bf2f(pe);
      }
      if ((wid & 1) == 0) rs[mL * 33 + l31] = part;
      acc[mb][0][r] = part;  // stash for wave-n 1 pass (reuse reg)
    }
  }
  __syncthreads();
  if (wid & 1) {
#pragma unroll
    for (int mb = 0; mb < 4; ++mb)
#pragma unroll
      for (int r = 0; r < 16; ++r) {
        const int mL = wmL + mb * 32 + (r & 3) + 8 * (r >> 2) + 4 * hi5;
        rs[mL * 33 + l31] += acc[mb][0][r];
      }
  }
  __syncthreads();
  if (tid < 256) {
    float s = 0.f;
#pragma unroll
    for (int j = 0; j < 32; ++j) s += rs[tid * 33 + j];
    atomicAdd(&aux[(long)b * sRes + m0 + tid], s);
  }
}

// per-(b,g) mean/rstd over contiguous 16*2048 = 32768 floats
__global__ __launch_bounds__(256) void gn_stats(const float* __restrict__ x,
                                                float* __restrict__ stats) {
  const int bg = blockIdx.x;
  const float4* p4 = (const float4*)(x + (long)bg * 32768);
  float s = 0.f, ss = 0.f;
  for (int i = threadIdx.x; i < 8192; i += 256) {
    const float4 u = p4[i];
    s += (u.x + u.y) + (u.z + u.w);
    ss += (u.x * u.x + u.y * u.y) + (u.z * u.z + u.w * u.w);
  }
#pragma unroll
  for (int off = 32; off > 0; off >>= 1) {
    s += __shfl_xor(s, off, 64);
    ss += __shfl_xor(ss, off, 64);
  }
  __shared__ float rsh[4], rss[4];
  const int lane = threadIdx.x & 63, wid = threadIdx.x >> 6;
  if (lane == 0) { rsh[wid] = s; rss[wid] = ss; }
  __syncthreads();
  if (threadIdx.x == 0) {
    s = rsh[0] + rsh[1] + rsh[2] + rsh[3];
    ss = rss[0] + rss[1] + rss[2] + rss[3];
    const float mean = s * (1.f / 32768.f);
    const float var = ss * (1.f / 32768.f) - mean * mean;
    stats[bg * 2] = mean;
    stats[bg * 2 + 1] = rsqrtf(var + 1e-6f);
  }
}

// normalize + affine, write hT[b][n][c] bf16 (64x64 LDS-tiled transpose)
__global__ __launch_bounds__(256) void gn_apply_t(
    const float* __restrict__ x, const float* __restrict__ stats,
    const float* __restrict__ gamma, const float* __restrict__ beta,
    u16* __restrict__ hT) {
  const int b = blockIdx.z, c0 = blockIdx.y * 64, n0 = blockIdx.x * 64;
  __shared__ u16 t[64][72];
  const int tid = threadIdx.x;
  const float* px = x + ((long)b * 512 + c0) * 2048 + n0;
#pragma unroll
  for (int i = 0; i < 4; ++i) {
    const int idx = tid + i * 256;
    const int r = idx >> 4, q4 = (idx & 15) * 4;
    const float4 u = *(const float4*)(px + (long)r * 2048 + q4);
    const int c = c0 + r, g = c >> 4;
    const float mean = stats[(b * 32 + g) * 2];
    const float rstd = stats[(b * 32 + g) * 2 + 1];
    const float ga = gamma[c] * rstd;
    const float be = beta[c] - mean * ga;
    t[r][q4 + 0] = f2bf(u.x * ga + be);
    t[r][q4 + 1] = f2bf(u.y * ga + be);
    t[r][q4 + 2] = f2bf(u.z * ga + be);
    t[r][q4 + 3] = f2bf(u.w * ga + be);
  }
  __syncthreads();
#pragma unroll
  for (int i = 0; i < 2; ++i) {
    const int idx = tid + i * 256;
    const int nr = idx >> 3, cc = (idx & 7) * 8;
    short8 w;
#pragma unroll
    for (int j = 0; j < 8; ++j) w[j] = (short)t[cc + j][nr];
    *(short8*)(hT + ((long)b * 2048 + n0 + nr) * 512 + c0 + cc) = w;
  }
}

// convert the 4 fp32 512x512 weights to bf16 (contiguous -> wq|wk|wv|wp)
__global__ __launch_bounds__(256) void cvt_w(const float* __restrict__ w0,
                                             const float* __restrict__ w1,
                                             const float* __restrict__ w2,
                                             const float* __restrict__ w3,
                                             u16* __restrict__ out) {
  const int z = blockIdx.y;
  const float* src = (z == 0) ? w0 : (z == 1) ? w1 : (z == 2) ? w2 : w3;
  const int i = blockIdx.x * 256 + threadIdx.x;
  out[(long)z * 262144 + i] = f2bf(src[i]);
}

// concat bq|bk -> bqk[1024]; also zero rowsum[16384] (runs before S-GEMM)
__global__ __launch_bounds__(256) void cvt_bias_zero(const float* __restrict__ bq,
                                                     const float* __restrict__ bk,
                                                     float* __restrict__ bqk,
                                                     float* __restrict__ rowsum) {
  const int i = blockIdx.x * 256 + threadIdx.x;
  if (i < 1024) bqk[i] = (i < 512) ? bq[i] : bk[i - 512];
  if (i < 16384) rowsum[i] = 0.f;
}

// rowsum -> 1/rowsum in place
__global__ __launch_bounds__(256) void rowinv(float* __restrict__ rowsum) {
  const int i = blockIdx.x * 256 + threadIdx.x;
  rowsum[i] = 1.f / rowsum[i];
}

extern "C" void kernel_launch(void* const* d_in, const int* in_sizes, int n_in,
                              void* d_out, int out_size, void* d_ws, size_t ws_size,
                              hipStream_t stream) {
  const float* x = (const float*)d_in[0];
  const float* gs = (const float*)d_in[1];
  const float* gb = (const float*)d_in[2];
  const float* wq = (const float*)d_in[3];
  const float* bq = (const float*)d_in[4];
  const float* wk = (const float*)d_in[5];
  const float* bk = (const float*)d_in[6];
  const float* wv = (const float*)d_in[7];
  const float* bv = (const float*)d_in[8];
  const float* wp = (const float*)d_in[9];
  const float* bp = (const float*)d_in[10];

  char* ws = (char*)d_ws;
  float* stats = (float*)ws;               // 2 KB
  float* bqk = (float*)(ws + 4096);        // 4 KB
  float* rowsum = (float*)(ws + 12288);    // 64 KB [B*2048]
  u16* hT = (u16*)(ws + 131072);           // [16384, 512] bf16, 16 MB
  u16* qkT = hT + 8388608;                 // [16384, 1024] bf16, 32 MB (q|k)
  u16* vv = qkT + 16777216;                // [B, 512, 2048] bf16, 16 MB
  u16* S = vv + 8388608;                   // [B, 2048, 2048] bf16, 64 MB (holds exp(s))
  u16* wb = S + 33554432;                  // wq|wk|wv|wp bf16, 2 MB
  u16* attnT = hT;                         // alias: hT dead after qk + v GEMMs
  float* out = (float*)d_out;

  cvt_w<<<dim3(1024, 4, 1), 256, 0, stream>>>(wq, wk, wv, wp, wb);
  cvt_bias_zero<<<dim3(64), 256, 0, stream>>>(bq, bk, bqk, rowsum);
  gn_stats<<<dim3(256), 256, 0, stream>>>(x, stats);
  gn_apply_t<<<dim3(32, 8, 8), 256, 0, stream>>>(x, stats, gs, gb, hT);

  // qk: M=16384 (m0=by*256+b*2048), N=1024, K=512; per-b 8m x 8n -> 512 blocks
  gemm14<0><<<dim3(512), 256, 0, stream>>>(
      hT, wb, qkT, bqk, nullptr, 512, 512, 512, 1024, 8, 2048, 0, 0, 0, 0, 0.f);
  // v: M=512, N=2048, K=512; per-b 2m x 16n -> 256 blocks
  gemm14<1><<<dim3(256), 256, 0, stream>>>(
      wb + 524288, hT, vv, bv, nullptr, 512, 512, 512, 2048, 16, 0, 0, 1048576, 1048576, 0, 0.f);
  // S: M=N=2048, K=512; per-b 8m x 16n -> 1024 blocks; writes exp(s*scale) + row sums
  gemm14<2><<<dim3(1024), 256, 0, stream>>>(
      qkT, qkT + 512, S, nullptr, rowsum, 512, 1024, 1024, 2048, 16, 0, 2097152, 2097152,
      4194304, 2048, 0.04419417382415922f);
  rowinv<<<dim3(64), 256, 0, stream>>>(rowsum);
  // PV: M=2048, N=512, K=2048; per-b 8m x 4n -> 256 blocks; epilogue * rinv[row]
  gemm14<5><<<dim3(256), 256, 0, stream>>>(
      S, vv, attnT, nullptr, rowsum, 2048, 2048, 2048, 512, 4, 0, 4194304, 1048576,
      1048576, 2048, 0.f);
  // proj+residual: M=512, N=2048, K=512; per-b 2m x 16n -> 256 blocks
  gemm14<4><<<dim3(256), 256, 0, stream>>>(
      wb + 786432, attnT, out, bp, (float*)x, 512, 512, 512, 2048, 16, 0, 0, 1048576, 1048576,
      1048576, 0.f);
}

// Round 17
// 184.160 us; speedup vs baseline: 1.2498x; 1.2498x over previous
//
#include <hip/hip_runtime.h>
#include <hip/hip_bf16.h>

// AttnBlock: B=8, C=512, N=2048, G=32.
// All GEMMs NT: Out[m][n] = sum_k A[m][k] * Bt[n][k].
// R17 = R15 (best: 181us) + aux-kernel consolidation:
//   - gn_fused: stats (pass1 64MB HBM) + normalize/transpose (pass2, L2/L3-hot
//     re-read) in ONE kernel, one block per (b,g). Saves a 64MB read + a launch.
//   - rowinv kernel dropped: PV (MODE 5) divides by rowsum directly.
//   - bias-concat + rowsum-zero folded into cvt_w.
// GEMM core LOCKED (m97 structure, 16x16x32): 9 schedule nulls + 32x32-shape
// failure (R16: 3.1M bank conflicts from the 32-row fragment pattern).
// Keeps: T2 swizzle (0 conflicts), batch->XCD pinning, S-epilogue exp+LDS-reduce
// rowsum (1 atomic/row), PV / rowsum, proj + bias + residual.

typedef __attribute__((ext_vector_type(8))) short short8;
typedef __attribute__((ext_vector_type(4))) float f32x4;
typedef unsigned short u16;

#define BK 64

__device__ __forceinline__ u16 f2bf(float f) {
  __hip_bfloat16 h = __float2bfloat16(f);
  return __builtin_bit_cast(u16, h);
}
__device__ __forceinline__ float bf2f(u16 u) {
  return __uint_as_float(((unsigned)u) << 16);
}

__device__ __forceinline__ void gload_lds16(const void* g, void* l) {
  __builtin_amdgcn_global_load_lds((const __attribute__((address_space(1))) void*)g,
                                   (__attribute__((address_space(3))) void*)l, 16, 0, 0);
}

// MODE 0: bf16 out = acc + bias[col]     MODE 1: bf16 out = acc + bias[row]
// MODE 2: bf16 out = exp(acc*scale); LDS-reduced row sums -> 1 atomicAdd/row
// MODE 4: f32  out = acc + bias[row] + aux[b*sRes + row*ldo + col]  (residual)
// MODE 5: bf16 out = acc / aux[b*sRes + row]                        (rowsum)
// Grid: 1-D, gid = t*8 + b;  t = by*GX + bx;  m0 = by*128 + b*mOffB; n0 = bx*128.
template <int MODE>
__global__ __launch_bounds__(256) void gemm13(
    const u16* __restrict__ A, const u16* __restrict__ Bt, void* __restrict__ OutV,
    const float* __restrict__ bias, float* __restrict__ aux,
    int K, int lda, int ldb, int ldo, int GX, int mOffB,
    long sA, long sBt, long sOut, long sRes, float scale) {
  __shared__ __align__(16) u16 lds_all[2 * 128 * BK];  // 32 KB: As | Bs
  u16* As = lds_all;
  u16* Bs = lds_all + 128 * BK;

  const int gid = blockIdx.x;
  const int b = gid & 7;  // batch == XCD (round-robin dispatch)
  const int t0 = gid >> 3;
  const int bx = t0 % GX;
  const int by = t0 / GX;
  const u16* Ab = A + (long)b * sA;
  const u16* Bb = Bt + (long)b * sBt;
  const int tid = threadIdx.x;
  const int lane = tid & 63;
  const int wid = tid >> 6;
  const int wm = (wid >> 1) * 64;
  const int wn = (wid & 1) * 64;
  const int m0 = by * 128 + b * mOffB;
  const int n0 = bx * 128;
  const int l15 = lane & 15;
  const int lhi = lane >> 4;
  const int sw = l15 & 7;  // swizzle term: 16B-slot ^= (row&7), row ≡ l15 (mod 16)

  f32x4 acc[4][4];
#pragma unroll
  for (int i = 0; i < 4; ++i)
#pragma unroll
    for (int j = 0; j < 4; ++j) acc[i][j] = (f32x4){0.f, 0.f, 0.f, 0.f};

  for (int ks = 0; ks < K; ks += BK) {
#pragma unroll
    for (int i = 0; i < 4; ++i) {
      const int c = tid + i * 256;
      const int row = c >> 3;
      const int gslot = (c & 7) ^ (row & 7);
      gload_lds16(Ab + (long)(m0 + row) * lda + ks + gslot * 8, (void*)(As + c * 8));
    }
#pragma unroll
    for (int i = 0; i < 4; ++i) {
      const int c = tid + i * 256;
      const int row = c >> 3;
      const int gslot = (c & 7) ^ (row & 7);
      gload_lds16(Bb + (long)(n0 + row) * ldb + ks + gslot * 8, (void*)(Bs + c * 8));
    }
    __syncthreads();

#pragma unroll
    for (int kh = 0; kh < 2; ++kh) {
      short8 af[4], bf[4];
#pragma unroll
      for (int mf = 0; mf < 4; ++mf)
        af[mf] = *(const short8*)(As + (wm + mf * 16 + l15) * BK +
                                  ((kh * 4 + lhi) ^ sw) * 8);
#pragma unroll
      for (int nf = 0; nf < 4; ++nf)
        bf[nf] = *(const short8*)(Bs + (wn + nf * 16 + l15) * BK +
                                  ((kh * 4 + lhi) ^ sw) * 8);
#pragma unroll
      for (int mf = 0; mf < 4; ++mf)
#pragma unroll
        for (int nf = 0; nf < 4; ++nf)
          acc[mf][nf] = __builtin_amdgcn_mfma_f32_16x16x32_bf16(af[mf], bf[nf],
                                                                acc[mf][nf], 0, 0, 0);
    }
    __syncthreads();
  }

  // epilogue: D row=(lane>>4)*4+reg (m), col=lane&15 (n)
  const int rbase = m0 + wm + lhi * 4;
  const int cbase = n0 + wn + l15;
  if constexpr (MODE == 2) {
    // exp(s*scale) store + LDS-reduced per-row sums (GEMM LDS dead after last barrier)
    float* rs = (float*)lds_all;  // [128][33] floats (pad 33: conflict-free reduce reads)
#pragma unroll
    for (int mf = 0; mf < 4; ++mf) {
#pragma unroll
      for (int i = 0; i < 4; ++i) {
        const int rl = wm + mf * 16 + lhi * 4 + i;  // local row 0..127
        const int row = m0 + rl;
        float rsum = 0.f;
#pragma unroll
        for (int nf = 0; nf < 4; ++nf) {
          const int col = cbase + nf * 16;
          const long oidx = (long)b * sOut + (long)row * ldo + col;
          const u16 pe = f2bf(__expf(acc[mf][nf][i] * scale));
          ((u16*)OutV)[oidx] = pe;
          rsum += bf2f(pe);  // sum what PV will actually read
        }
        rs[rl * 33 + (wn >> 2) + l15] = rsum;  // cols 0..15 (wn=0) / 16..31 (wn=64)
      }
    }
    __syncthreads();
    if (tid < 128) {
      float s = 0.f;
#pragma unroll
      for (int j = 0; j < 32; ++j) s += rs[tid * 33 + j];
      atomicAdd(&aux[(long)b * sRes + m0 + tid], s);
    }
  } else {
#pragma unroll
    for (int mf = 0; mf < 4; ++mf) {
#pragma unroll
      for (int nf = 0; nf < 4; ++nf) {
#pragma unroll
        for (int i = 0; i < 4; ++i) {
          const int row = rbase + mf * 16 + i;
          const int col = cbase + nf * 16;
          const long oidx = (long)b * sOut + (long)row * ldo + col;
          const float v = acc[mf][nf][i];
          if (MODE == 0) {
            ((u16*)OutV)[oidx] = f2bf(v + bias[col]);
          } else if (MODE == 1) {
            ((u16*)OutV)[oidx] = f2bf(v + bias[row]);
          } else if (MODE == 5) {
            ((u16*)OutV)[oidx] = f2bf(v / aux[(long)b * sRes + row]);
          } else {
            const float r = aux[(long)b * sRes + (long)row * ldo + col];
            ((float*)OutV)[oidx] = v + bias[row] + r;
          }
        }
      }
    }
  }
}

// Fused GroupNorm: one block per (b,g); gid = g*8 + b (XCD-pinned).
// Pass 1: mean/rstd over the 16x2048 slice (64MB HBM total).
// Pass 2: re-read slice (L2/L3-hot), normalize+affine, write hT[b][n][c] bf16
//         via 16x64 LDS transpose tiles.
__global__ __launch_bounds__(256) void gn_fused(
    const float* __restrict__ x, const float* __restrict__ gamma,
    const float* __restrict__ beta, u16* __restrict__ hT) {
  const int gid = blockIdx.x;
  const int b = gid & 7;
  const int g = gid >> 3;
  const float* px = x + ((long)b * 512 + g * 16) * 2048;
  const int tid = threadIdx.x;
  const int lane = tid & 63, wid = tid >> 6;

  // pass 1: sum / sumsq over 32768 floats
  const float4* p4 = (const float4*)px;
  float s = 0.f, ss = 0.f;
  for (int i = tid; i < 8192; i += 256) {
    const float4 u = p4[i];
    s += (u.x + u.y) + (u.z + u.w);
    ss += (u.x * u.x + u.y * u.y) + (u.z * u.z + u.w * u.w);
  }
#pragma unroll
  for (int off = 32; off > 0; off >>= 1) {
    s += __shfl_xor(s, off, 64);
    ss += __shfl_xor(ss, off, 64);
  }
  __shared__ float rs4[4], rss4[4], bc[2];
  if (lane == 0) { rs4[wid] = s; rss4[wid] = ss; }
  __syncthreads();
  if (tid == 0) {
    s = rs4[0] + rs4[1] + rs4[2] + rs4[3];
    ss = rss4[0] + rss4[1] + rss4[2] + rss4[3];
    const float mean = s * (1.f / 32768.f);
    const float var = ss * (1.f / 32768.f) - mean * mean;
    bc[0] = mean;
    bc[1] = rsqrtf(var + 1e-6f);
  }
  __shared__ float ga[16], be[16];
  __syncthreads();
  if (tid < 16) {
    const float gaa = gamma[g * 16 + tid] * bc[1];
    ga[tid] = gaa;
    be[tid] = beta[g * 16 + tid] - bc[0] * gaa;
  }
  __syncthreads();

  // pass 2: 32 chunks of (16c x 64n) -> transpose -> hT[b][n][g*16 + c]
  __shared__ u16 t[16][68];
  for (int ch = 0; ch < 32; ++ch) {
    const int n0 = ch * 64;
    const int c = tid >> 4;       // 0..15
    const int nq = tid & 15;      // 0..15
    const float4 u = *(const float4*)(px + (long)c * 2048 + n0 + nq * 4);
    t[c][nq * 4 + 0] = f2bf(u.x * ga[c] + be[c]);
    t[c][nq * 4 + 1] = f2bf(u.y * ga[c] + be[c]);
    t[c][nq * 4 + 2] = f2bf(u.z * ga[c] + be[c]);
    t[c][nq * 4 + 3] = f2bf(u.w * ga[c] + be[c]);
    __syncthreads();
    const int n = tid >> 2;       // 0..63
    const int cq = tid & 3;       // 0..3
    ushort4 w;
    w.x = t[cq * 4 + 0][n];
    w.y = t[cq * 4 + 1][n];
    w.z = t[cq * 4 + 2][n];
    w.w = t[cq * 4 + 3][n];
    *(ushort4*)(hT + ((long)b * 2048 + n0 + n) * 512 + g * 16 + cq * 4) = w;
    __syncthreads();
  }
}

// weights fp32->bf16 (wq|wk|wv|wp); z==0 blocks also: bqk concat + rowsum zero
__global__ __launch_bounds__(256) void cvt_w(const float* __restrict__ w0,
                                             const float* __restrict__ w1,
                                             const float* __restrict__ w2,
                                             const float* __restrict__ w3,
                                             const float* __restrict__ bq,
                                             const float* __restrict__ bk,
                                             float* __restrict__ bqk,
                                             float* __restrict__ rowsum,
                                             u16* __restrict__ out) {
  const int z = blockIdx.y;
  const float* src = (z == 0) ? w0 : (z == 1) ? w1 : (z == 2) ? w2 : w3;
  const int i = blockIdx.x * 256 + threadIdx.x;
  out[(long)z * 262144 + i] = f2bf(src[i]);
  if (z == 0) {
    if (i < 1024) bqk[i] = (i < 512) ? bq[i] : bk[i - 512];
    if (i < 16384) rowsum[i] = 0.f;
  }
}

extern "C" void kernel_launch(void* const* d_in, const int* in_sizes, int n_in,
                              void* d_out, int out_size, void* d_ws, size_t ws_size,
                              hipStream_t stream) {
  const float* x = (const float*)d_in[0];
  const float* gs = (const float*)d_in[1];
  const float* gb = (const float*)d_in[2];
  const float* wq = (const float*)d_in[3];
  const float* bq = (const float*)d_in[4];
  const float* wk = (const float*)d_in[5];
  const float* bk = (const float*)d_in[6];
  const float* wv = (const float*)d_in[7];
  const float* bv = (const float*)d_in[8];
  const float* wp = (const float*)d_in[9];
  const float* bp = (const float*)d_in[10];

  char* ws = (char*)d_ws;
  float* bqk = (float*)(ws + 4096);        // 4 KB
  float* rowsum = (float*)(ws + 12288);    // 64 KB [B*2048]
  u16* hT = (u16*)(ws + 131072);           // [16384, 512] bf16, 16 MB
  u16* qkT = hT + 8388608;                 // [16384, 1024] bf16, 32 MB (q|k)
  u16* vv = qkT + 16777216;                // [B, 512, 2048] bf16, 16 MB
  u16* S = vv + 8388608;                   // [B, 2048, 2048] bf16, 64 MB (holds exp(s))
  u16* wb = S + 33554432;                  // wq|wk|wv|wp bf16, 2 MB
  u16* attnT = hT;                         // alias: hT dead after qk + v GEMMs
  float* out = (float*)d_out;

  cvt_w<<<dim3(1024, 4, 1), 256, 0, stream>>>(wq, wk, wv, wp, bq, bk, bqk, rowsum, wb);
  gn_fused<<<dim3(256), 256, 0, stream>>>(x, gs, gb, hT);

  // qk: M=16384 (m0=by*128+b*2048), N=1024, K=512; per-b 16m x 8n -> 1024 blocks
  gemm13<0><<<dim3(1024), 256, 0, stream>>>(
      hT, wb, qkT, bqk, nullptr, 512, 512, 512, 1024, 8, 2048, 0, 0, 0, 0, 0.f);
  // v: M=512, N=2048, K=512; per-b 4m x 16n -> 512 blocks
  gemm13<1><<<dim3(512), 256, 0, stream>>>(
      wb + 524288, hT, vv, bv, nullptr, 512, 512, 512, 2048, 16, 0, 0, 1048576, 1048576, 0, 0.f);
  // S: M=N=2048, K=512; per-b 16m x 16n -> 2048 blocks; writes exp(s*scale) + row sums
  gemm13<2><<<dim3(2048), 256, 0, stream>>>(
      qkT, qkT + 512, S, nullptr, rowsum, 512, 1024, 1024, 2048, 16, 0, 2097152, 2097152,
      4194304, 2048, 0.04419417382415922f);
  // PV: M=2048, N=512, K=2048; per-b 16m x 4n -> 512 blocks; epilogue / rowsum[row]
  gemm13<5><<<dim3(512), 256, 0, stream>>>(
      S, vv, attnT, nullptr, rowsum, 2048, 2048, 2048, 512, 4, 0, 4194304, 1048576,
      1048576, 2048, 0.f);
  // proj+residual: M=512, N=2048, K=512; per-b 4m x 16n -> 512 blocks
  gemm13<4><<<dim3(512), 256, 0, stream>>>(
      wb + 786432, attnT, out, bp, (float*)x, 512, 512, 512, 2048, 16, 0, 0, 1048576, 1048576,
      1048576, 0.f);
}

// Round 18
// 172.164 us; speedup vs baseline: 1.3369x; 1.0697x over previous
//
#include <hip/hip_runtime.h>
#include <hip/hip_bf16.h>

// AttnBlock: B=8, C=512, N=2048, G=32.
// All GEMMs NT: Out[m][n] = sum_k A[m][k] * Bt[n][k].
// R18 = R15 (best: 181us) + single-pass register-resident GroupNorm:
//   gn_reg: thread t owns n in {4t..4t+3, 1024+4t..+3} for ALL 16 channels of its
//   (b,g) slice under the coalesced float4 striding -> pack x to bf16x2 in 64 VGPRs
//   during the stats pass, then write transposed hT rows straight from registers
//   (no second 64MB read, no LDS transpose, one kernel instead of two).
// rowinv dropped (PV divides by rowsum); bias-concat + rowsum-zero folded in cvt_w.
// GEMM core LOCKED (m97 128x128, 16x16x32; 9 schedule nulls + 32x32 shape failure).
// Keeps: T2 swizzle, batch->XCD pinning, S-epilogue exp + LDS rowsum reduce.

typedef __attribute__((ext_vector_type(8))) short short8;
typedef __attribute__((ext_vector_type(4))) float f32x4;
typedef unsigned short u16;
typedef unsigned int u32;

#define BK 64

__device__ __forceinline__ u16 f2bf(float f) {
  __hip_bfloat16 h = __float2bfloat16(f);
  return __builtin_bit_cast(u16, h);
}
__device__ __forceinline__ float bf2f(u16 u) {
  return __uint_as_float(((u32)u) << 16);
}

__device__ __forceinline__ void gload_lds16(const void* g, void* l) {
  __builtin_amdgcn_global_load_lds((const __attribute__((address_space(1))) void*)g,
                                   (__attribute__((address_space(3))) void*)l, 16, 0, 0);
}

// MODE 0: bf16 out = acc + bias[col]     MODE 1: bf16 out = acc + bias[row]
// MODE 2: bf16 out = exp(acc*scale); LDS-reduced row sums -> 1 atomicAdd/row
// MODE 4: f32  out = acc + bias[row] + aux[b*sRes + row*ldo + col]  (residual)
// MODE 5: bf16 out = acc / aux[b*sRes + row]                        (rowsum)
// Grid: 1-D, gid = t*8 + b;  t = by*GX + bx;  m0 = by*128 + b*mOffB; n0 = bx*128.
template <int MODE>
__global__ __launch_bounds__(256) void gemm13(
    const u16* __restrict__ A, const u16* __restrict__ Bt, void* __restrict__ OutV,
    const float* __restrict__ bias, float* __restrict__ aux,
    int K, int lda, int ldb, int ldo, int GX, int mOffB,
    long sA, long sBt, long sOut, long sRes, float scale) {
  __shared__ __align__(16) u16 lds_all[2 * 128 * BK];  // 32 KB: As | Bs
  u16* As = lds_all;
  u16* Bs = lds_all + 128 * BK;

  const int gid = blockIdx.x;
  const int b = gid & 7;  // batch == XCD (round-robin dispatch)
  const int t0 = gid >> 3;
  const int bx = t0 % GX;
  const int by = t0 / GX;
  const u16* Ab = A + (long)b * sA;
  const u16* Bb = Bt + (long)b * sBt;
  const int tid = threadIdx.x;
  const int lane = tid & 63;
  const int wid = tid >> 6;
  const int wm = (wid >> 1) * 64;
  const int wn = (wid & 1) * 64;
  const int m0 = by * 128 + b * mOffB;
  const int n0 = bx * 128;
  const int l15 = lane & 15;
  const int lhi = lane >> 4;
  const int sw = l15 & 7;  // swizzle term: 16B-slot ^= (row&7), row ≡ l15 (mod 16)

  f32x4 acc[4][4];
#pragma unroll
  for (int i = 0; i < 4; ++i)
#pragma unroll
    for (int j = 0; j < 4; ++j) acc[i][j] = (f32x4){0.f, 0.f, 0.f, 0.f};

  for (int ks = 0; ks < K; ks += BK) {
#pragma unroll
    for (int i = 0; i < 4; ++i) {
      const int c = tid + i * 256;
      const int row = c >> 3;
      const int gslot = (c & 7) ^ (row & 7);
      gload_lds16(Ab + (long)(m0 + row) * lda + ks + gslot * 8, (void*)(As + c * 8));
    }
#pragma unroll
    for (int i = 0; i < 4; ++i) {
      const int c = tid + i * 256;
      const int row = c >> 3;
      const int gslot = (c & 7) ^ (row & 7);
      gload_lds16(Bb + (long)(n0 + row) * ldb + ks + gslot * 8, (void*)(Bs + c * 8));
    }
    __syncthreads();

#pragma unroll
    for (int kh = 0; kh < 2; ++kh) {
      short8 af[4], bf[4];
#pragma unroll
      for (int mf = 0; mf < 4; ++mf)
        af[mf] = *(const short8*)(As + (wm + mf * 16 + l15) * BK +
                                  ((kh * 4 + lhi) ^ sw) * 8);
#pragma unroll
      for (int nf = 0; nf < 4; ++nf)
        bf[nf] = *(const short8*)(Bs + (wn + nf * 16 + l15) * BK +
                                  ((kh * 4 + lhi) ^ sw) * 8);
#pragma unroll
      for (int mf = 0; mf < 4; ++mf)
#pragma unroll
        for (int nf = 0; nf < 4; ++nf)
          acc[mf][nf] = __builtin_amdgcn_mfma_f32_16x16x32_bf16(af[mf], bf[nf],
                                                                acc[mf][nf], 0, 0, 0);
    }
    __syncthreads();
  }

  // epilogue: D row=(lane>>4)*4+reg (m), col=lane&15 (n)
  const int rbase = m0 + wm + lhi * 4;
  const int cbase = n0 + wn + l15;
  if constexpr (MODE == 2) {
    float* rs = (float*)lds_all;  // [128][33] floats (pad 33: conflict-free reduce reads)
#pragma unroll
    for (int mf = 0; mf < 4; ++mf) {
#pragma unroll
      for (int i = 0; i < 4; ++i) {
        const int rl = wm + mf * 16 + lhi * 4 + i;  // local row 0..127
        const int row = m0 + rl;
        float rsum = 0.f;
#pragma unroll
        for (int nf = 0; nf < 4; ++nf) {
          const int col = cbase + nf * 16;
          const long oidx = (long)b * sOut + (long)row * ldo + col;
          const u16 pe = f2bf(__expf(acc[mf][nf][i] * scale));
          ((u16*)OutV)[oidx] = pe;
          rsum += bf2f(pe);  // sum what PV will actually read
        }
        rs[rl * 33 + (wn >> 2) + l15] = rsum;  // cols 0..15 (wn=0) / 16..31 (wn=64)
      }
    }
    __syncthreads();
    if (tid < 128) {
      float s = 0.f;
#pragma unroll
      for (int j = 0; j < 32; ++j) s += rs[tid * 33 + j];
      atomicAdd(&aux[(long)b * sRes + m0 + tid], s);
    }
  } else {
#pragma unroll
    for (int mf = 0; mf < 4; ++mf) {
#pragma unroll
      for (int nf = 0; nf < 4; ++nf) {
#pragma unroll
        for (int i = 0; i < 4; ++i) {
          const int row = rbase + mf * 16 + i;
          const int col = cbase + nf * 16;
          const long oidx = (long)b * sOut + (long)row * ldo + col;
          const float v = acc[mf][nf][i];
          if (MODE == 0) {
            ((u16*)OutV)[oidx] = f2bf(v + bias[col]);
          } else if (MODE == 1) {
            ((u16*)OutV)[oidx] = f2bf(v + bias[row]);
          } else if (MODE == 5) {
            ((u16*)OutV)[oidx] = f2bf(v / aux[(long)b * sRes + row]);
          } else {
            const float r = aux[(long)b * sRes + (long)row * ldo + col];
            ((float*)OutV)[oidx] = v + bias[row] + r;
          }
        }
      }
    }
  }
}

// Single-pass register-resident GroupNorm + transpose. One block per (b,g),
// gid = g*8 + b (XCD-pinned). Thread t's float4 stride (tid + 256j) owns
// c = j>>1, n4 = t + 256*(j&1)  ->  columns n in {4t..4t+3, 1024+4t..+3} for
// ALL 16 channels. Stats + bf16-pack in one read; hT written from registers.
__global__ __launch_bounds__(256) void gn_reg(
    const float* __restrict__ x, const float* __restrict__ gamma,
    const float* __restrict__ beta, u16* __restrict__ hT) {
  const int gid = blockIdx.x;
  const int b = gid & 7;
  const int g = gid >> 3;
  const float* px = x + ((long)b * 512 + g * 16) * 2048;
  const int tid = threadIdx.x;
  const int lane = tid & 63, wid = tid >> 6;

  u32 pk[64];  // 32 float4 -> 64 bf16x2 words; pk[2j],pk[2j+1] for j = 2c+(n-half)
  float s = 0.f, ss = 0.f;
#pragma unroll
  for (int j = 0; j < 32; ++j) {
    const float4 u = ((const float4*)px)[tid + 256 * j];
    s += (u.x + u.y) + (u.z + u.w);
    ss += (u.x * u.x + u.y * u.y) + (u.z * u.z + u.w * u.w);
    pk[2 * j] = (u32)f2bf(u.x) | ((u32)f2bf(u.y) << 16);
    pk[2 * j + 1] = (u32)f2bf(u.z) | ((u32)f2bf(u.w) << 16);
  }
#pragma unroll
  for (int off = 32; off > 0; off >>= 1) {
    s += __shfl_xor(s, off, 64);
    ss += __shfl_xor(ss, off, 64);
  }
  __shared__ float rs4[4], rss4[4], ga[16], be[16];
  if (lane == 0) { rs4[wid] = s; rss4[wid] = ss; }
  __syncthreads();
  if (tid == 0) {
    s = rs4[0] + rs4[1] + rs4[2] + rs4[3];
    ss = rss4[0] + rss4[1] + rss4[2] + rss4[3];
    const float mean = s * (1.f / 32768.f);
    const float var = ss * (1.f / 32768.f) - mean * mean;
    rs4[0] = mean;
    rss4[0] = rsqrtf(var + 1e-6f);
  }
  __syncthreads();
  if (tid < 16) {
    const float gaa = gamma[g * 16 + tid] * rss4[0];
    ga[tid] = gaa;
    be[tid] = beta[g * 16 + tid] - rs4[0] * gaa;
  }
  __syncthreads();

  float gar[16], ber[16];
#pragma unroll
  for (int c = 0; c < 16; ++c) { gar[c] = ga[c]; ber[c] = be[c]; }

  // write hT rows n = 4t+r (+1024 for p=1): 16 channels = 2 x 16B stores per row
#pragma unroll
  for (int p = 0; p < 2; ++p) {
#pragma unroll
    for (int r = 0; r < 4; ++r) {
      const int n = 4 * tid + r + 1024 * p;
      u16 w[16];
#pragma unroll
      for (int c = 0; c < 16; ++c) {
        const u32 word = pk[2 * (2 * c + p) + (r >> 1)];
        const float xv = bf2f((u16)(word >> (16 * (r & 1))));
        w[c] = f2bf(xv * gar[c] + ber[c]);
      }
      u16* dst = hT + ((long)b * 2048 + n) * 512 + g * 16;
      *(short8*)dst = *(short8*)&w[0];
      *(short8*)(dst + 8) = *(short8*)&w[8];
    }
  }
}

// weights fp32->bf16 (wq|wk|wv|wp); z==0 blocks also: bqk concat + rowsum zero
__global__ __launch_bounds__(256) void cvt_w(const float* __restrict__ w0,
                                             const float* __restrict__ w1,
                                             const float* __restrict__ w2,
                                             const float* __restrict__ w3,
                                             const float* __restrict__ bq,
                                             const float* __restrict__ bk,
                                             float* __restrict__ bqk,
                                             float* __restrict__ rowsum,
                                             u16* __restrict__ out) {
  const int z = blockIdx.y;
  const float* src = (z == 0) ? w0 : (z == 1) ? w1 : (z == 2) ? w2 : w3;
  const int i = blockIdx.x * 256 + threadIdx.x;
  out[(long)z * 262144 + i] = f2bf(src[i]);
  if (z == 0) {
    if (i < 1024) bqk[i] = (i < 512) ? bq[i] : bk[i - 512];
    if (i < 16384) rowsum[i] = 0.f;
  }
}

extern "C" void kernel_launch(void* const* d_in, const int* in_sizes, int n_in,
                              void* d_out, int out_size, void* d_ws, size_t ws_size,
                              hipStream_t stream) {
  const float* x = (const float*)d_in[0];
  const float* gs = (const float*)d_in[1];
  const float* gb = (const float*)d_in[2];
  const float* wq = (const float*)d_in[3];
  const float* bq = (const float*)d_in[4];
  const float* wk = (const float*)d_in[5];
  const float* bk = (const float*)d_in[6];
  const float* wv = (const float*)d_in[7];
  const float* bv = (const float*)d_in[8];
  const float* wp = (const float*)d_in[9];
  const float* bp = (const float*)d_in[10];

  char* ws = (char*)d_ws;
  float* bqk = (float*)(ws + 4096);        // 4 KB
  float* rowsum = (float*)(ws + 12288);    // 64 KB [B*2048]
  u16* hT = (u16*)(ws + 131072);           // [16384, 512] bf16, 16 MB
  u16* qkT = hT + 8388608;                 // [16384, 1024] bf16, 32 MB (q|k)
  u16* vv = qkT + 16777216;                // [B, 512, 2048] bf16, 16 MB
  u16* S = vv + 8388608;                   // [B, 2048, 2048] bf16, 64 MB (holds exp(s))
  u16* wb = S + 33554432;                  // wq|wk|wv|wp bf16, 2 MB
  u16* attnT = hT;                         // alias: hT dead after qk + v GEMMs
  float* out = (float*)d_out;

  cvt_w<<<dim3(1024, 4, 1), 256, 0, stream>>>(wq, wk, wv, wp, bq, bk, bqk, rowsum, wb);
  gn_reg<<<dim3(256), 256, 0, stream>>>(x, gs, gb, hT);

  // qk: M=16384 (m0=by*128+b*2048), N=1024, K=512; per-b 16m x 8n -> 1024 blocks
  gemm13<0><<<dim3(1024), 256, 0, stream>>>(
      hT, wb, qkT, bqk, nullptr, 512, 512, 512, 1024, 8, 2048, 0, 0, 0, 0, 0.f);
  // v: M=512, N=2048, K=512; per-b 4m x 16n -> 512 blocks
  gemm13<1><<<dim3(512), 256, 0, stream>>>(
      wb + 524288, hT, vv, bv, nullptr, 512, 512, 512, 2048, 16, 0, 0, 1048576, 1048576, 0, 0.f);
  // S: M=N=2048, K=512; per-b 16m x 16n -> 2048 blocks; writes exp(s*scale) + row sums
  gemm13<2><<<dim3(2048), 256, 0, stream>>>(
      qkT, qkT + 512, S, nullptr, rowsum, 512, 1024, 1024, 2048, 16, 0, 2097152, 2097152,
      4194304, 2048, 0.04419417382415922f);
  // PV: M=2048, N=512, K=2048; per-b 16m x 4n -> 512 blocks; epilogue / rowsum[row]
  gemm13<5><<<dim3(512), 256, 0, stream>>>(
      S, vv, attnT, nullptr, rowsum, 2048, 2048, 2048, 512, 4, 0, 4194304, 1048576,
      1048576, 2048, 0.f);
  // proj+residual: M=512, N=2048, K=512; per-b 4m x 16n -> 512 blocks
  gemm13<4><<<dim3(512), 256, 0, stream>>>(
      wb + 786432, attnT, out, bp, (float*)x, 512, 512, 512, 2048, 16, 0, 0, 1048576, 1048576,
      1048576, 0.f);
}

// Round 19
// 154.146 us; speedup vs baseline: 1.4931x; 1.1169x over previous
//
#include <hip/hip_runtime.h>
#include <hip/hip_bf16.h>
#include <hip/hip_fp8.h>

// AttnBlock: B=8, C=512, N=2048, G=32.
// All GEMMs NT: Out[m][n] = sum_k A[m][k] * Bt[n][k].
// R19 = R18 (172us) + fp8(e4m3 OCP) for the attention core:
//   - qk GEMM outputs q,k as fp8; v GEMM outputs v as fp8.
//   - gemm_f8: S and PV run fp8_fp8 MFMA (bf16 rate, but HALF the staged bytes)
//     with BK=128 fp8 elements -> 128B rows, byte-identical staging+swizzle to
//     the proven bf16-BK64 tile; half the K-tiles -> half the barriers.
//   - S epilogue: exp(s*scale) -> fp8 P + LDS rowsum reduce (sums what PV reads).
//   - PV epilogue: acc / rowsum -> bf16 attnT.
// GEMM structure LOCKED (m97 128x128; 9 schedule nulls + 32x32 shape failure).
// Keeps: T2 swizzle, batch->XCD pinning, gn_reg single-pass GN, fused epilogues.

typedef __attribute__((ext_vector_type(8))) short short8;
typedef __attribute__((ext_vector_type(4))) float f32x4;
typedef unsigned short u16;
typedef unsigned char u8;
typedef unsigned int u32;

#define BK 64

__device__ __forceinline__ u16 f2bf(float f) {
  __hip_bfloat16 h = __float2bfloat16(f);
  return __builtin_bit_cast(u16, h);
}
__device__ __forceinline__ float bf2f(u16 u) {
  return __uint_as_float(((u32)u) << 16);
}
__device__ __forceinline__ u8 f2fp8(float f) {
  __hip_fp8_e4m3 h(f);
  return __builtin_bit_cast(u8, h);
}
__device__ __forceinline__ float fp82f(u8 u) {
  __hip_fp8_e4m3 h = __builtin_bit_cast(__hip_fp8_e4m3, u);
  return (float)h;
}

__device__ __forceinline__ void gload_lds16(const void* g, void* l) {
  __builtin_amdgcn_global_load_lds((const __attribute__((address_space(1))) void*)g,
                                   (__attribute__((address_space(3))) void*)l, 16, 0, 0);
}

// bf16 GEMM (qk / v / proj).
// MODE 0: fp8 out = acc + bias[col]   MODE 1: fp8 out = acc + bias[row]
// MODE 4: f32 out = acc + bias[row] + aux[b*sRes + row*ldo + col] (residual)
template <int MODE>
__global__ __launch_bounds__(256) void gemm13(
    const u16* __restrict__ A, const u16* __restrict__ Bt, void* __restrict__ OutV,
    const float* __restrict__ bias, float* __restrict__ aux,
    int K, int lda, int ldb, int ldo, int GX, int mOffB,
    long sA, long sBt, long sOut, long sRes, float scale) {
  __shared__ __align__(16) u16 lds_all[2 * 128 * BK];  // 32 KB: As | Bs
  u16* As = lds_all;
  u16* Bs = lds_all + 128 * BK;

  const int gid = blockIdx.x;
  const int b = gid & 7;  // batch == XCD (round-robin dispatch)
  const int t0 = gid >> 3;
  const int bx = t0 % GX;
  const int by = t0 / GX;
  const u16* Ab = A + (long)b * sA;
  const u16* Bb = Bt + (long)b * sBt;
  const int tid = threadIdx.x;
  const int lane = tid & 63;
  const int wid = tid >> 6;
  const int wm = (wid >> 1) * 64;
  const int wn = (wid & 1) * 64;
  const int m0 = by * 128 + b * mOffB;
  const int n0 = bx * 128;
  const int l15 = lane & 15;
  const int lhi = lane >> 4;
  const int sw = l15 & 7;

  f32x4 acc[4][4];
#pragma unroll
  for (int i = 0; i < 4; ++i)
#pragma unroll
    for (int j = 0; j < 4; ++j) acc[i][j] = (f32x4){0.f, 0.f, 0.f, 0.f};

  for (int ks = 0; ks < K; ks += BK) {
#pragma unroll
    for (int i = 0; i < 4; ++i) {
      const int c = tid + i * 256;
      const int row = c >> 3;
      const int gslot = (c & 7) ^ (row & 7);
      gload_lds16(Ab + (long)(m0 + row) * lda + ks + gslot * 8, (void*)(As + c * 8));
    }
#pragma unroll
    for (int i = 0; i < 4; ++i) {
      const int c = tid + i * 256;
      const int row = c >> 3;
      const int gslot = (c & 7) ^ (row & 7);
      gload_lds16(Bb + (long)(n0 + row) * ldb + ks + gslot * 8, (void*)(Bs + c * 8));
    }
    __syncthreads();

#pragma unroll
    for (int kh = 0; kh < 2; ++kh) {
      short8 af[4], bf[4];
#pragma unroll
      for (int mf = 0; mf < 4; ++mf)
        af[mf] = *(const short8*)(As + (wm + mf * 16 + l15) * BK +
                                  ((kh * 4 + lhi) ^ sw) * 8);
#pragma unroll
      for (int nf = 0; nf < 4; ++nf)
        bf[nf] = *(const short8*)(Bs + (wn + nf * 16 + l15) * BK +
                                  ((kh * 4 + lhi) ^ sw) * 8);
#pragma unroll
      for (int mf = 0; mf < 4; ++mf)
#pragma unroll
        for (int nf = 0; nf < 4; ++nf)
          acc[mf][nf] = __builtin_amdgcn_mfma_f32_16x16x32_bf16(af[mf], bf[nf],
                                                                acc[mf][nf], 0, 0, 0);
    }
    __syncthreads();
  }

  const int rbase = m0 + wm + lhi * 4;
  const int cbase = n0 + wn + l15;
#pragma unroll
  for (int mf = 0; mf < 4; ++mf) {
#pragma unroll
    for (int nf = 0; nf < 4; ++nf) {
#pragma unroll
      for (int i = 0; i < 4; ++i) {
        const int row = rbase + mf * 16 + i;
        const int col = cbase + nf * 16;
        const long oidx = (long)b * sOut + (long)row * ldo + col;
        const float v = acc[mf][nf][i];
        if (MODE == 0) {
          ((u8*)OutV)[oidx] = f2fp8(v + bias[col]);
        } else if (MODE == 1) {
          ((u8*)OutV)[oidx] = f2fp8(v + bias[row]);
        } else {
          const float r = aux[(long)b * sRes + (long)row * ldo + col];
          ((float*)OutV)[oidx] = v + bias[row] + r;
        }
      }
    }
  }
}

// fp8 GEMM (S / PV). BK=128 fp8 elements = 128B rows (byte-identical staging
// and swizzle to the bf16-BK64 tile). lda/ldb/ldo in u8 elements.
// MODE 2: fp8 out = exp(acc*scale); LDS rowsum reduce -> 1 atomicAdd/row
// MODE 5: bf16 out = acc / aux[b*sRes + row]
template <int MODE>
__global__ __launch_bounds__(256) void gemm_f8(
    const u8* __restrict__ A, const u8* __restrict__ Bt, void* __restrict__ OutV,
    float* __restrict__ aux,
    int K, int lda, int ldb, int ldo, int GX, int mOffB,
    long sA, long sBt, long sOut, long sRes, float scale) {
  __shared__ __align__(16) u8 lds_all[2 * 128 * 128];  // 32 KB: As | Bs
  u8* As = lds_all;
  u8* Bs = lds_all + 128 * 128;

  const int gid = blockIdx.x;
  const int b = gid & 7;
  const int t0 = gid >> 3;
  const int bx = t0 % GX;
  const int by = t0 / GX;
  const u8* Ab = A + (long)b * sA;
  const u8* Bb = Bt + (long)b * sBt;
  const int tid = threadIdx.x;
  const int lane = tid & 63;
  const int wid = tid >> 6;
  const int wm = (wid >> 1) * 64;
  const int wn = (wid & 1) * 64;
  const int m0 = by * 128 + b * mOffB;
  const int n0 = bx * 128;
  const int l15 = lane & 15;
  const int lhi = lane >> 4;
  const int sw = l15 & 7;

  f32x4 acc[4][4];
#pragma unroll
  for (int i = 0; i < 4; ++i)
#pragma unroll
    for (int j = 0; j < 4; ++j) acc[i][j] = (f32x4){0.f, 0.f, 0.f, 0.f};

  for (int ks = 0; ks < K; ks += 128) {
    // stage 128x128B per operand: 1024 chunks, 4/thread; row = c>>3, slot = c&7
#pragma unroll
    for (int i = 0; i < 4; ++i) {
      const int c = tid + i * 256;
      const int row = c >> 3;
      const int gslot = (c & 7) ^ (row & 7);
      gload_lds16(Ab + (long)(m0 + row) * lda + ks + gslot * 16, (void*)(As + c * 16));
    }
#pragma unroll
    for (int i = 0; i < 4; ++i) {
      const int c = tid + i * 256;
      const int row = c >> 3;
      const int gslot = (c & 7) ^ (row & 7);
      gload_lds16(Bb + (long)(n0 + row) * ldb + ks + gslot * 16, (void*)(Bs + c * 16));
    }
    __syncthreads();

#pragma unroll
    for (int kk = 0; kk < 4; ++kk) {  // four K=32 fp8 substeps
      long af[4], bf[4];
      const int so = ((((kk << 1) + (lhi >> 1)) ^ sw) << 4) + (lhi & 1) * 8;
#pragma unroll
      for (int mf = 0; mf < 4; ++mf)
        af[mf] = *(const long*)(As + (wm + mf * 16 + l15) * 128 + so);
#pragma unroll
      for (int nf = 0; nf < 4; ++nf)
        bf[nf] = *(const long*)(Bs + (wn + nf * 16 + l15) * 128 + so);
#pragma unroll
      for (int mf = 0; mf < 4; ++mf)
#pragma unroll
        for (int nf = 0; nf < 4; ++nf)
          acc[mf][nf] = __builtin_amdgcn_mfma_f32_16x16x32_fp8_fp8(af[mf], bf[nf],
                                                                   acc[mf][nf], 0, 0, 0);
    }
    __syncthreads();
  }

  const int cbase = n0 + wn + l15;
  if constexpr (MODE == 2) {
    float* rs = (float*)lds_all;  // [128][33] floats (dead GEMM LDS)
#pragma unroll
    for (int mf = 0; mf < 4; ++mf) {
#pragma unroll
      for (int i = 0; i < 4; ++i) {
        const int rl = wm + mf * 16 + lhi * 4 + i;
        const int row = m0 + rl;
        float rsum = 0.f;
#pragma unroll
        for (int nf = 0; nf < 4; ++nf) {
          const int col = cbase + nf * 16;
          const long oidx = (long)b * sOut + (long)row * ldo + col;
          const u8 pe = f2fp8(__expf(acc[mf][nf][i] * scale));
          ((u8*)OutV)[oidx] = pe;
          rsum += fp82f(pe);  // sum what PV will actually read
        }
        rs[rl * 33 + (wn >> 2) + l15] = rsum;
      }
    }
    __syncthreads();
    if (tid < 128) {
      float s = 0.f;
#pragma unroll
      for (int j = 0; j < 32; ++j) s += rs[tid * 33 + j];
      atomicAdd(&aux[(long)b * sRes + m0 + tid], s);
    }
  } else {
    const int rbase = m0 + wm + lhi * 4;
#pragma unroll
    for (int mf = 0; mf < 4; ++mf) {
#pragma unroll
      for (int nf = 0; nf < 4; ++nf) {
#pragma unroll
        for (int i = 0; i < 4; ++i) {
          const int row = rbase + mf * 16 + i;
          const int col = cbase + nf * 16;
          const long oidx = (long)b * sOut + (long)row * ldo + col;
          ((u16*)OutV)[oidx] = f2bf(acc[mf][nf][i] / aux[(long)b * sRes + row]);
        }
      }
    }
  }
}

// Single-pass register-resident GroupNorm + transpose (R18-proven).
__global__ __launch_bounds__(256) void gn_reg(
    const float* __restrict__ x, const float* __restrict__ gamma,
    const float* __restrict__ beta, u16* __restrict__ hT) {
  const int gid = blockIdx.x;
  const int b = gid & 7;
  const int g = gid >> 3;
  const float* px = x + ((long)b * 512 + g * 16) * 2048;
  const int tid = threadIdx.x;
  const int lane = tid & 63, wid = tid >> 6;

  u32 pk[64];
  float s = 0.f, ss = 0.f;
#pragma unroll
  for (int j = 0; j < 32; ++j) {
    const float4 u = ((const float4*)px)[tid + 256 * j];
    s += (u.x + u.y) + (u.z + u.w);
    ss += (u.x * u.x + u.y * u.y) + (u.z * u.z + u.w * u.w);
    pk[2 * j] = (u32)f2bf(u.x) | ((u32)f2bf(u.y) << 16);
    pk[2 * j + 1] = (u32)f2bf(u.z) | ((u32)f2bf(u.w) << 16);
  }
#pragma unroll
  for (int off = 32; off > 0; off >>= 1) {
    s += __shfl_xor(s, off, 64);
    ss += __shfl_xor(ss, off, 64);
  }
  __shared__ float rs4[4], rss4[4], ga[16], be[16];
  if (lane == 0) { rs4[wid] = s; rss4[wid] = ss; }
  __syncthreads();
  if (tid == 0) {
    s = rs4[0] + rs4[1] + rs4[2] + rs4[3];
    ss = rss4[0] + rss4[1] + rss4[2] + rss4[3];
    const float mean = s * (1.f / 32768.f);
    const float var = ss * (1.f / 32768.f) - mean * mean;
    rs4[0] = mean;
    rss4[0] = rsqrtf(var + 1e-6f);
  }
  __syncthreads();
  if (tid < 16) {
    const float gaa = gamma[g * 16 + tid] * rss4[0];
    ga[tid] = gaa;
    be[tid] = beta[g * 16 + tid] - rs4[0] * gaa;
  }
  __syncthreads();

  float gar[16], ber[16];
#pragma unroll
  for (int c = 0; c < 16; ++c) { gar[c] = ga[c]; ber[c] = be[c]; }

#pragma unroll
  for (int p = 0; p < 2; ++p) {
#pragma unroll
    for (int r = 0; r < 4; ++r) {
      const int n = 4 * tid + r + 1024 * p;
      u16 w[16];
#pragma unroll
      for (int c = 0; c < 16; ++c) {
        const u32 word = pk[2 * (2 * c + p) + (r >> 1)];
        const float xv = bf2f((u16)(word >> (16 * (r & 1))));
        w[c] = f2bf(xv * gar[c] + ber[c]);
      }
      u16* dst = hT + ((long)b * 2048 + n) * 512 + g * 16;
      *(short8*)dst = *(short8*)&w[0];
      *(short8*)(dst + 8) = *(short8*)&w[8];
    }
  }
}

// weights fp32->bf16 (wq|wk|wv|wp); z==0 blocks also: bqk concat + rowsum zero
__global__ __launch_bounds__(256) void cvt_w(const float* __restrict__ w0,
                                             const float* __restrict__ w1,
                                             const float* __restrict__ w2,
                                             const float* __restrict__ w3,
                                             const float* __restrict__ bq,
                                             const float* __restrict__ bk,
                                             float* __restrict__ bqk,
                                             float* __restrict__ rowsum,
                                             u16* __restrict__ out) {
  const int z = blockIdx.y;
  const float* src = (z == 0) ? w0 : (z == 1) ? w1 : (z == 2) ? w2 : w3;
  const int i = blockIdx.x * 256 + threadIdx.x;
  out[(long)z * 262144 + i] = f2bf(src[i]);
  if (z == 0) {
    if (i < 1024) bqk[i] = (i < 512) ? bq[i] : bk[i - 512];
    if (i < 16384) rowsum[i] = 0.f;
  }
}

extern "C" void kernel_launch(void* const* d_in, const int* in_sizes, int n_in,
                              void* d_out, int out_size, void* d_ws, size_t ws_size,
                              hipStream_t stream) {
  const float* x = (const float*)d_in[0];
  const float* gs = (const float*)d_in[1];
  const float* gb = (const float*)d_in[2];
  const float* wq = (const float*)d_in[3];
  const float* bq = (const float*)d_in[4];
  const float* wk = (const float*)d_in[5];
  const float* bk = (const float*)d_in[6];
  const float* wv = (const float*)d_in[7];
  const float* bv = (const float*)d_in[8];
  const float* wp = (const float*)d_in[9];
  const float* bp = (const float*)d_in[10];

  char* ws = (char*)d_ws;
  float* bqk = (float*)(ws + 4096);        // 4 KB
  float* rowsum = (float*)(ws + 12288);    // 64 KB [B*2048]
  u16* hT = (u16*)(ws + 131072);           // [16384, 512] bf16, 16 MB
  u8* qkT8 = (u8*)(hT + 8388608);          // [16384, 1024] fp8, 16 MB (q|k)
  u8* vv8 = qkT8 + 16777216;               // [B, 512, 2048] fp8, 8 MB
  u8* S8 = vv8 + 8388608;                  // [B, 2048, 2048] fp8, 32 MB (holds P)
  u16* wb = (u16*)(S8 + 33554432);         // wq|wk|wv|wp bf16, 2 MB
  u16* attnT = hT;                         // alias: hT dead after qk + v GEMMs
  float* out = (float*)d_out;

  cvt_w<<<dim3(1024, 4, 1), 256, 0, stream>>>(wq, wk, wv, wp, bq, bk, bqk, rowsum, wb);
  gn_reg<<<dim3(256), 256, 0, stream>>>(x, gs, gb, hT);

  // qk: M=16384 (m0=by*128+b*2048), N=1024, K=512 -> fp8 out; 1024 blocks
  gemm13<0><<<dim3(1024), 256, 0, stream>>>(
      hT, wb, qkT8, bqk, nullptr, 512, 512, 512, 1024, 8, 2048, 0, 0, 0, 0, 0.f);
  // v: M=512, N=2048, K=512 -> fp8 out; per-b 4m x 16n -> 512 blocks
  gemm13<1><<<dim3(512), 256, 0, stream>>>(
      wb + 524288, hT, vv8, bv, nullptr, 512, 512, 512, 2048, 16, 0, 0, 1048576,
      1048576, 0, 0.f);
  // S: fp8 GEMM, M=N=2048, K=512; per-b 16m x 16n -> 2048 blocks; exp + rowsum
  gemm_f8<2><<<dim3(2048), 256, 0, stream>>>(
      qkT8, qkT8 + 512, S8, rowsum, 512, 1024, 1024, 2048, 16, 0, 2097152, 2097152,
      4194304, 2048, 0.04419417382415922f);
  // PV: fp8 GEMM, M=2048, N=512, K=2048; per-b 16m x 4n -> 512 blocks; / rowsum
  gemm_f8<5><<<dim3(512), 256, 0, stream>>>(
      S8, vv8, attnT, rowsum, 2048, 2048, 2048, 512, 4, 0, 4194304, 1048576,
      1048576, 2048, 0.f);
  // proj+residual: M=512, N=2048, K=512; per-b 4m x 16n -> 512 blocks
  gemm13<4><<<dim3(512), 256, 0, stream>>>(
      wb + 786432, attnT, out, bp, (float*)x, 512, 512, 512, 2048, 16, 0, 0, 1048576,
      1048576, 1048576, 0.f);
}